// Round 5
// baseline (341.833 us; speedup 1.0000x reference)
//
#include <hip/hip_runtime.h>
#include <math.h>

#define EPS 1e-6f
// B=2, C=256, N=32768 (32^3), g=8, heads=4, d=64

typedef __attribute__((ext_vector_type(8))) short bhalf8;
typedef __attribute__((ext_vector_type(4))) float floatx4;

__device__ __forceinline__ unsigned short f2bf(float f) {
    union { float f; unsigned u; } v; v.f = f;
    unsigned r = (v.u + 0x7fffu + ((v.u >> 16) & 1u)) >> 16;
    return (unsigned short)r;
}

// ---------------- K1: weight prep (blocks 0..255) + avg-pool (blocks 256..767) ----------------
// W1b/W2b chunked bf16 [kc][o][32]: W1b[kc*8192 + o*32 + (c&31)], kc = c>>5
// A[o] = sum_c q_w[o][c]*nq_w[c],  Bc[o] = sum_c q_w[o][c]*nq_b[c]
__global__ void pre1(const float* __restrict__ q_w,
                     const float* __restrict__ proj_w,
                     const float* __restrict__ nq_w,
                     const float* __restrict__ nq_b,
                     unsigned short* __restrict__ W1b,
                     unsigned short* __restrict__ W2b,
                     float* __restrict__ A, float* __restrict__ Bc,
                     const float* __restrict__ x1, float* __restrict__ tokens) {
    if (blockIdx.x < 256) {
        int o = blockIdx.x;
        int c = threadIdx.x;
        float qv = q_w[o * 256 + c];
        float pv = proj_w[o * 256 + c];
        float w1 = qv * nq_w[c];
        int kc = c >> 5, kk = c & 31;
        W1b[kc * 8192 + o * 32 + kk] = f2bf(w1);
        W2b[kc * 8192 + o * 32 + kk] = f2bf(pv);
        float bcv = qv * nq_b[c];
        __shared__ float sA[4], sB[4];
        float a = w1, b = bcv;
        for (int off = 32; off > 0; off >>= 1) {
            a += __shfl_down(a, off);
            b += __shfl_down(b, off);
        }
        int wave = threadIdx.x >> 6, lane = threadIdx.x & 63;
        if (lane == 0) { sA[wave] = a; sB[wave] = b; }
        __syncthreads();
        if (threadIdx.x == 0) {
            A[o]  = sA[0] + sA[1] + sA[2] + sA[3];
            Bc[o] = sB[0] + sB[1] + sB[2] + sB[3];
        }
    } else {
        int bc = blockIdx.x - 256;  // b*256 + c
        const float* base = x1 + (size_t)bc * 4096;
        int wave = threadIdx.x >> 6;
        int lane = threadIdx.x & 63;
        int doff = lane >> 3, hoff = lane & 7;
        for (int t = wave * 2; t < wave * 2 + 2; ++t) {
            int gd = t >> 2, gh = (t >> 1) & 1, gw = t & 1;
            const float* p = base + (gd * 8 + doff) * 256 + (gh * 8 + hoff) * 16 + gw * 8;
            float4 v0 = *(const float4*)p;
            float4 v1 = *(const float4*)(p + 4);
            float s = v0.x + v0.y + v0.z + v0.w + v1.x + v1.y + v1.z + v1.w;
            for (int off = 32; off > 0; off >>= 1) s += __shfl_down(s, off);
            if (lane == 0) tokens[bc * 8 + t] = s * (1.0f / 512.0f);
        }
    }
}

// ---------------- K2: dwconv + residual + LN + k/v projection -> MFMA fragment layouts ----------------
// kfragG[b][h][kc][lane 64][j 8] bf16: element K[g=lane&15][d=kc*32+(lane>>4)*8+j], rows g>=8 zeroed.
// vfragG[b][h][dtile][l 16][g 8] bf16: element V[g][d=dtile*16+l] (A-frag for PV, lanes 16..63 zero).
__global__ void tokens_all(const float* __restrict__ tokens,
                           const float* __restrict__ dw_w,
                           const float* __restrict__ nkv_w,
                           const float* __restrict__ nkv_b,
                           const float* __restrict__ k_w,
                           const float* __restrict__ v_w,
                           unsigned short* __restrict__ kfragG,
                           unsigned short* __restrict__ vfragG) {
    int b = blockIdx.x >> 6;
    int og = blockIdx.x & 63;
    int c = threadIdx.x;
    __shared__ float t2[256][9];
    __shared__ float u8[8], r8[8];
    float t[8];
    #pragma unroll
    for (int g = 0; g < 8; ++g) t[g] = tokens[(b * 256 + c) * 8 + g];
    float w[27];
    #pragma unroll
    for (int i = 0; i < 27; ++i) w[i] = dw_w[c * 27 + i];
    #pragma unroll
    for (int z = 0; z < 2; ++z)
    #pragma unroll
    for (int y = 0; y < 2; ++y)
    #pragma unroll
    for (int x = 0; x < 2; ++x) {
        float s = 0.f;
        #pragma unroll
        for (int i = 0; i < 3; ++i) {
            int nz = z + i - 1; if (nz < 0 || nz > 1) continue;
            #pragma unroll
            for (int j = 0; j < 3; ++j) {
                int ny = y + j - 1; if (ny < 0 || ny > 1) continue;
                #pragma unroll
                for (int l = 0; l < 3; ++l) {
                    int nx = x + l - 1; if (nx < 0 || nx > 1) continue;
                    s += w[(i * 3 + j) * 3 + l] * t[nz * 4 + ny * 2 + nx];
                }
            }
        }
        int g = z * 4 + y * 2 + x;
        t2[c][g] = t[g] + s;
    }
    __syncthreads();
    if (c < 8) {
        float su = 0.f, sq = 0.f;
        for (int cc = 0; cc < 256; ++cc) { float v = t2[cc][c]; su += v; sq += v * v; }
        float u = su * (1.f / 256.f);
        float var = sq * (1.f / 256.f) - u * u;
        u8[c] = u;
        r8[c] = rsqrtf(var + EPS);
    }
    __syncthreads();
    int wv = threadIdx.x >> 6;
    int lane = threadIdx.x & 63;
    int o = og * 4 + wv;
    float acck[8] = {0,0,0,0,0,0,0,0}, accv[8] = {0,0,0,0,0,0,0,0};
    #pragma unroll
    for (int i = 0; i < 4; ++i) {
        int cc = lane + 64 * i;
        float kw = k_w[o * 256 + cc];
        float vw = v_w[o * 256 + cc];
        float nw = nkv_w[cc], nb2 = nkv_b[cc];
        #pragma unroll
        for (int g = 0; g < 8; ++g) {
            float tv = t2[cc][g];
            acck[g] += kw * (nw * (tv - u8[g]) * r8[g] + nb2);
            accv[g] += vw * tv;
        }
    }
    #pragma unroll
    for (int g = 0; g < 8; ++g)
        for (int off = 32; off > 0; off >>= 1) {
            acck[g] += __shfl_down(acck[g], off);
            accv[g] += __shfl_down(accv[g], off);
        }
    if (lane == 0) {
        int h = o >> 6, dl = o & 63;
        // K fragment scatter (this channel o is the "d" row for head h)
        int kc = dl >> 5, dd = (dl >> 3) & 3, j = dl & 7;
        unsigned short* kb = kfragG + (size_t)(((b * 4 + h) * 2 + kc) * 512) + j;
        #pragma unroll
        for (int g = 0; g < 8; ++g) {
            kb[(g + 16 * dd) * 8] = f2bf(acck[g]);
            kb[(g + 8 + 16 * dd) * 8] = 0;   // zero rows g>=8 of the A-operand
        }
        // V fragment: contiguous 8 bf16
        int dt = dl >> 4, l15 = dl & 15;
        uint4 pk;
        pk.x = (unsigned)f2bf(accv[0]) | ((unsigned)f2bf(accv[1]) << 16);
        pk.y = (unsigned)f2bf(accv[2]) | ((unsigned)f2bf(accv[3]) << 16);
        pk.z = (unsigned)f2bf(accv[4]) | ((unsigned)f2bf(accv[5]) << 16);
        pk.w = (unsigned)f2bf(accv[6]) | ((unsigned)f2bf(accv[7]) << 16);
        *(uint4*)(vfragG + (size_t)(((b * 4 + h) * 4 + dt) * 128) + l15 * 8) = pk;
    }
}

// ---------------- K3: fully fused, 8 waves x 64 positions, MFMA attention ----------------
// LDS 40960 B (XQ 32768 + SCR 8192) -> 4 blocks/CU (32 waves). __launch_bounds__(512,8): VGPR cap 64
// (= round-4 measured usage; attention per-thread state shrank from o2[32]+q4 to MFMA frags).
// K/V staged NOWHERE: loaded per-wave as MFMA fragments from global (L2-hot, written by tokens_all).
// Attention per wave (h=w&3, n-half=w>>2): QK^T = 2 chained mfma(K_frag, q_frag) per 16-n tile;
// softmax = 4 exp/lane + 2 shfl_xor(16) (P rows g>=8 zeroed for the PV B-operand);
// PV = mfma(V^T_frag, P_frag) -- P's B-frag layout IS QK's C layout, stays in registers.
// Barriers: B1 staging->GEMM1, B2 ->epilogue, B2b epilogue q->attention (cross-wave), B3 ->GEMM2.
// SCR aliasing: stats part/As/Bs/us/rs (dead by B2b) reused as store-transpose scratch post-B3
// (16x16 per wave, XOR-swizzled col^(row&12) -> no pad, conflict-lite).
__global__ __launch_bounds__(512, 8)
void fused2(const float* __restrict__ x2,
            const unsigned short* __restrict__ W1b,
            const unsigned short* __restrict__ W2b,
            const float* __restrict__ Ag, const float* __restrict__ Bg,
            const unsigned short* __restrict__ kfragG,
            const unsigned short* __restrict__ vfragG,
            float* __restrict__ out) {
    __shared__ __align__(16) unsigned short XQ[16384];   // 32768 B
    __shared__ __align__(16) float SCR[2048];            // 8192 B
    float* part = SCR;          // [1024] stats partials
    float* As   = SCR + 1024;   // [256]
    float* Bs   = SCR + 1280;   // [256]
    float* us   = SCR + 1536;   // [64]
    float* rs   = SCR + 1600;   // [64]

    const int tid = threadIdx.x;
    const int w = tid >> 6;
    const int lane = tid & 63;
    const int m = lane & 15;
    const int qd = lane >> 4;
    const int n0g = blockIdx.x * 64;
    const int b = n0g >> 15;
    const int pos0 = n0g & 32767;

    if (tid < 256) { As[tid] = Ag[tid]; Bs[tid] = Bg[tid]; }
    const unsigned short* w1p = W1b + (size_t)(32 * w + m) * 32 + qd * 8;
    bhalf8 af1_0 = *(const bhalf8*)(w1p);
    bhalf8 af1_1 = *(const bhalf8*)(w1p + 512);

    // ---- stage: x fp32 -> stats partials + bf16 swizzled tile ----
    {
        const int n4 = tid & 15, cg = tid >> 4;   // cg 0..31
        const float* xb = x2 + (size_t)b * 8388608 + pos0 + n4 * 4;
        float su[4] = {0,0,0,0}, sq[4] = {0,0,0,0};
        #pragma unroll
        for (int cc = 0; cc < 4; ++cc) {
            int p = cg + 32 * cc;   // c-pair 0..127
            int c0 = 2 * p;
            float4 a  = *(const float4*)(xb + (size_t)c0 * 32768);
            float4 bq = *(const float4*)(xb + (size_t)(c0 + 1) * 32768);
            int g = p >> 2, wsub = p & 3;
            float av[4] = {a.x, a.y, a.z, a.w};
            float bv[4] = {bq.x, bq.y, bq.z, bq.w};
            #pragma unroll
            for (int i = 0; i < 4; ++i) {
                su[i] += av[i] + bv[i];
                sq[i] += av[i] * av[i] + bv[i] * bv[i];
                int row = 4 * n4 + i;
                int swz = ((row >> 2) ^ row) & 7;
                unsigned val = (unsigned)f2bf(av[i]) | ((unsigned)f2bf(bv[i]) << 16);
                ((unsigned*)XQ)[row * 128 + ((g ^ swz) << 2) + wsub] = val;
            }
        }
        #pragma unroll
        for (int i = 0; i < 4; ++i) {
            float a2 = su[i], q2 = sq[i];
            a2 += __shfl_down(a2, 16); q2 += __shfl_down(q2, 16);
            a2 += __shfl_down(a2, 32); q2 += __shfl_down(q2, 32);
            if (lane < 16) {
                part[w * 128 + (4 * lane + i) * 2]     = a2;
                part[w * 128 + (4 * lane + i) * 2 + 1] = q2;
            }
        }
    }
    __syncthreads();   // B1

    if (tid < 64) {
        float S = 0.f, Q = 0.f;
        #pragma unroll
        for (int w8 = 0; w8 < 8; ++w8) {
            S += part[w8 * 128 + tid * 2];
            Q += part[w8 * 128 + tid * 2 + 1];
        }
        float mu = S * (1.f / 256.f);
        us[tid] = mu;
        rs[tid] = rsqrtf(Q * (1.f / 256.f) - mu * mu + EPS);
    }

    // ---- GEMM1 ----
    floatx4 acc[2][4];
    #pragma unroll
    for (int i = 0; i < 2; ++i)
        #pragma unroll
        for (int j = 0; j < 4; ++j)
            acc[i][j] = (floatx4){0.f, 0.f, 0.f, 0.f};
    {
        bhalf8 afb[2][2];
        afb[0][0] = af1_0; afb[0][1] = af1_1;
        #pragma unroll
        for (int kc = 0; kc < 8; ++kc) {
            if (kc < 7) {
                afb[(kc + 1) & 1][0] = *(const bhalf8*)(w1p + (kc + 1) * 8192);
                afb[(kc + 1) & 1][1] = *(const bhalf8*)(w1p + (kc + 1) * 8192 + 512);
            }
            bhalf8 bfr[4];
            #pragma unroll
            for (int nt = 0; nt < 4; ++nt) {
                int n = nt * 16 + m;
                int swz = ((n >> 2) ^ n) & 7;
                bfr[nt] = *(const bhalf8*)(XQ + n * 256 + (((4 * kc + qd) ^ swz) << 3));
            }
            #pragma unroll
            for (int t = 0; t < 2; ++t)
                #pragma unroll
                for (int nt = 0; nt < 4; ++nt)
                    acc[t][nt] = __builtin_amdgcn_mfma_f32_16x16x32_bf16(afb[kc & 1][t], bfr[nt], acc[t][nt], 0, 0, 0);
        }
    }
    const unsigned short* w2p = W2b + (size_t)(32 * w + m) * 32 + qd * 8;
    bhalf8 af2_0 = *(const bhalf8*)(w2p);
    bhalf8 af2_1 = *(const bhalf8*)(w2p + 512);
    __syncthreads();   // B2: x-tile free; us/rs visible

    // ---- epilogue 1: LN correction, q -> XQ ----
    #pragma unroll
    for (int t = 0; t < 2; ++t) {
        int ob = 32 * w + 16 * t + 4 * qd;
        floatx4 Af = *(const floatx4*)&As[ob];
        floatx4 Bf = *(const floatx4*)&Bs[ob];
        int gq = ob >> 3, off = ob & 7;
        #pragma unroll
        for (int nt = 0; nt < 4; ++nt) {
            int n = nt * 16 + m;
            int swz = ((n >> 2) ^ n) & 7;
            float uv = us[n], rv = rs[n];
            unsigned p0 = (unsigned)f2bf(rv * (acc[t][nt][0] - uv * Af[0]) + Bf[0])
                        | ((unsigned)f2bf(rv * (acc[t][nt][1] - uv * Af[1]) + Bf[1]) << 16);
            unsigned p1 = (unsigned)f2bf(rv * (acc[t][nt][2] - uv * Af[2]) + Bf[2])
                        | ((unsigned)f2bf(rv * (acc[t][nt][3] - uv * Af[3]) + Bf[3]) << 16);
            uint2 val; val.x = p0; val.y = p1;
            *(uint2*)(XQ + n * 256 + ((gq ^ swz) << 3) + off) = val;
        }
    }
    __syncthreads();   // B2b: q fully written before cross-wave attention reads

    // ---- attention (MFMA): wave w -> head h=w&3, n-half w>>2 ----
    {
        const int h = w & 3;
        const int nh = w >> 2;
        // K fragments: 2 x uint4/lane from global (L2-hot)
        uint4 kf0 = ((const uint4*)(kfragG + (size_t)((b * 4 + h) * 2 + 0) * 512))[lane];
        uint4 kf1 = ((const uint4*)(kfragG + (size_t)((b * 4 + h) * 2 + 1) * 512))[lane];
        // V^T fragments: lanes 0..15 hold data, others zero (B rows g>=8 are zero)
        uint4 vf[4];
        #pragma unroll
        for (int dt = 0; dt < 4; ++dt) {
            uint4 z; z.x = 0; z.y = 0; z.z = 0; z.w = 0;
            if (lane < 16) z = ((const uint4*)(vfragG + (size_t)((b * 4 + h) * 4 + dt) * 128))[lane];
            vf[dt] = z;
        }
        #pragma unroll
        for (int nt2 = 0; nt2 < 2; ++nt2) {
            const int n = (2 * nh + nt2) * 16 + m;
            const int swz = ((n >> 2) ^ n) & 7;
            unsigned short* qrow = XQ + n * 256;
            // QK^T: S[g][n], chained over d
            floatx4 s4 = (floatx4){0.f, 0.f, 0.f, 0.f};
            bhalf8 qf0 = *(const bhalf8*)(qrow + (((h * 8 + qd) ^ swz) << 3));
            bhalf8 qf1 = *(const bhalf8*)(qrow + (((h * 8 + 4 + qd) ^ swz) << 3));
            s4 = __builtin_amdgcn_mfma_f32_16x16x32_bf16(*(const bhalf8*)&kf0, qf0, s4, 0, 0, 0);
            s4 = __builtin_amdgcn_mfma_f32_16x16x32_bf16(*(const bhalf8*)&kf1, qf1, s4, 0, 0, 0);
            // softmax over g: lane holds g = 4*qd + j (valid for qd<2; rows 8..15 discarded)
            float sv0 = s4[0] * 0.125f, sv1 = s4[1] * 0.125f;
            float sv2 = s4[2] * 0.125f, sv3 = s4[3] * 0.125f;
            float m4 = fmaxf(fmaxf(sv0, sv1), fmaxf(sv2, sv3));
            float mm = fmaxf(m4, __shfl_xor(m4, 16));
            float p0 = __expf(sv0 - mm), p1 = __expf(sv1 - mm);
            float p2 = __expf(sv2 - mm), p3 = __expf(sv3 - mm);
            float ss = p0 + p1 + p2 + p3;
            float inv = 1.f / (ss + __shfl_xor(ss, 16));
            p0 *= inv; p1 *= inv; p2 *= inv; p3 *= inv;
            float e0 = __shfl_xor(p0, 16), e1 = __shfl_xor(p1, 16);
            float e2 = __shfl_xor(p2, 16), e3 = __shfl_xor(p3, 16);
            // P B-fragment: lanes qd==0 hold k-rows 0..7 (own g0..3 + partner g4..7), rest zero
            uint4 pbu; pbu.x = 0; pbu.y = 0; pbu.z = 0; pbu.w = 0;
            if (qd == 0) {
                pbu.x = (unsigned)f2bf(p0) | ((unsigned)f2bf(p1) << 16);
                pbu.y = (unsigned)f2bf(p2) | ((unsigned)f2bf(p3) << 16);
                pbu.z = (unsigned)f2bf(e0) | ((unsigned)f2bf(e1) << 16);
                pbu.w = (unsigned)f2bf(e2) | ((unsigned)f2bf(e3) << 16);
            }
            bhalf8 pb = *(const bhalf8*)&pbu;
            // PV: out^T[d][n] per 16-d tile; write bf16 to XQ (swizzled)
            #pragma unroll
            for (int dt = 0; dt < 4; ++dt) {
                floatx4 o4 = (floatx4){0.f, 0.f, 0.f, 0.f};
                o4 = __builtin_amdgcn_mfma_f32_16x16x32_bf16(*(const bhalf8*)&vf[dt], pb, o4, 0, 0, 0);
                int cb = h * 64 + dt * 16 + 4 * qd;   // + rr (0..3)
                int gl = cb >> 3;
                uint2 w2v;
                w2v.x = (unsigned)f2bf(o4[0]) | ((unsigned)f2bf(o4[1]) << 16);
                w2v.y = (unsigned)f2bf(o4[2]) | ((unsigned)f2bf(o4[3]) << 16);
                *(uint2*)(qrow + ((gl ^ swz) << 3) + (cb & 7)) = w2v;
            }
        }
    }
    __syncthreads();   // B3: attn out visible

    // ---- GEMM2 ----
    floatx4 acc2[2][4];
    #pragma unroll
    for (int i = 0; i < 2; ++i)
        #pragma unroll
        for (int j = 0; j < 4; ++j)
            acc2[i][j] = (floatx4){0.f, 0.f, 0.f, 0.f};
    {
        bhalf8 afb[2][2];
        afb[0][0] = af2_0; afb[0][1] = af2_1;
        #pragma unroll
        for (int kc = 0; kc < 8; ++kc) {
            if (kc < 7) {
                afb[(kc + 1) & 1][0] = *(const bhalf8*)(w2p + (kc + 1) * 8192);
                afb[(kc + 1) & 1][1] = *(const bhalf8*)(w2p + (kc + 1) * 8192 + 512);
            }
            bhalf8 bfr[4];
            #pragma unroll
            for (int nt = 0; nt < 4; ++nt) {
                int n = nt * 16 + m;
                int swz = ((n >> 2) ^ n) & 7;
                bfr[nt] = *(const bhalf8*)(XQ + n * 256 + (((4 * kc + qd) ^ swz) << 3));
            }
            #pragma unroll
            for (int t = 0; t < 2; ++t)
                #pragma unroll
                for (int nt = 0; nt < 4; ++nt)
                    acc2[t][nt] = __builtin_amdgcn_mfma_f32_16x16x32_bf16(afb[kc & 1][t], bfr[nt], acc2[t][nt], 0, 0, 0);
        }
    }

    // ---- store: per-wave 16x16 XOR-swizzled LDS transpose (SCR reuse) -> float4 stores ----
    {
        float* tb = SCR + w * 256;
        float* obase = out + (size_t)b * 8388608 + pos0;
        const int ol = lane >> 2, c4 = lane & 3;
        #pragma unroll
        for (int t = 0; t < 2; ++t) {
            #pragma unroll
            for (int nt = 0; nt < 4; ++nt) {
                #pragma unroll
                for (int rr = 0; rr < 4; ++rr) {
                    int row = qd * 4 + rr;
                    tb[row * 16 + (m ^ (row & 12))] = acc2[t][nt][rr];
                }
                float4 vo = *(const float4*)(tb + ol * 16 + ((c4 * 4) ^ (ol & 12)));
                *(float4*)(obase + (size_t)(32 * w + 16 * t + ol) * 32768 + nt * 16 + c4 * 4) = vo;
            }
        }
    }
}

extern "C" void kernel_launch(void* const* d_in, const int* in_sizes, int n_in,
                              void* d_out, int out_size, void* d_ws, size_t ws_size,
                              hipStream_t stream) {
    (void)in_sizes; (void)n_in; (void)out_size; (void)ws_size;
    const float* x2     = (const float*)d_in[0];
    const float* x1_low = (const float*)d_in[1];
    const float* q_w    = (const float*)d_in[2];
    const float* k_w    = (const float*)d_in[3];
    const float* v_w    = (const float*)d_in[4];
    const float* dw_w   = (const float*)d_in[5];
    const float* proj_w = (const float*)d_in[6];
    const float* nq_w   = (const float*)d_in[7];
    const float* nq_b   = (const float*)d_in[8];
    const float* nkv_w  = (const float*)d_in[9];
    const float* nkv_b  = (const float*)d_in[10];
    float* outp = (float*)d_out;

    float* wsf = (float*)d_ws;
    float* Av  = wsf;                                        // 256
    float* Bv  = wsf + 256;                                  // 256
    float* tk  = wsf + 512;                                  // 4096
    unsigned short* kfragG = (unsigned short*)(wsf + 4608);  // 8192 ushorts (2b x 4h x 2kc x 64 x 8)
    unsigned short* vfragG = (unsigned short*)(wsf + 8704);  // 4096 ushorts (2b x 4h x 4dt x 16 x 8)
    unsigned short* W1b = (unsigned short*)(wsf + 10752);    // 65536 ushorts
    unsigned short* W2b = (unsigned short*)(wsf + 43520);    // 65536 ushorts

    pre1<<<768, 256, 0, stream>>>(q_w, proj_w, nq_w, nq_b, W1b, W2b, Av, Bv, x1_low, tk);
    tokens_all<<<128, 256, 0, stream>>>(tk, dw_w, nkv_w, nkv_b, k_w, v_w, kfragG, vfragG);
    fused2<<<1024, 512, 0, stream>>>(x2, W1b, W2b, Av, Bv, kfragG, vfragG, outp);
}

// Round 6
// 166.579 us; speedup vs baseline: 2.0521x; 2.0521x over previous
//
#include <hip/hip_runtime.h>
#include <math.h>

#define EPS 1e-6f
// B=2, C=256, N=32768 (32^3), g=8, heads=4, d=64

typedef __attribute__((ext_vector_type(8))) short bhalf8;
typedef __attribute__((ext_vector_type(4))) float floatx4;

__device__ __forceinline__ unsigned short f2bf(float f) {
    union { float f; unsigned u; } v; v.f = f;
    unsigned r = (v.u + 0x7fffu + ((v.u >> 16) & 1u)) >> 16;
    return (unsigned short)r;
}

// ---------------- K1: weight prep (blocks 0..255) + avg-pool (blocks 256..767) ----------------
// W1b/W2b chunked bf16 [kc][o][32]: W1b[kc*8192 + o*32 + (c&31)], kc = c>>5
// A[o] = sum_c q_w[o][c]*nq_w[c],  Bc[o] = sum_c q_w[o][c]*nq_b[c]
__global__ void pre1(const float* __restrict__ q_w,
                     const float* __restrict__ proj_w,
                     const float* __restrict__ nq_w,
                     const float* __restrict__ nq_b,
                     unsigned short* __restrict__ W1b,
                     unsigned short* __restrict__ W2b,
                     float* __restrict__ A, float* __restrict__ Bc,
                     const float* __restrict__ x1, float* __restrict__ tokens) {
    if (blockIdx.x < 256) {
        int o = blockIdx.x;
        int c = threadIdx.x;
        float qv = q_w[o * 256 + c];
        float pv = proj_w[o * 256 + c];
        float w1 = qv * nq_w[c];
        int kc = c >> 5, kk = c & 31;
        W1b[kc * 8192 + o * 32 + kk] = f2bf(w1);
        W2b[kc * 8192 + o * 32 + kk] = f2bf(pv);
        float bcv = qv * nq_b[c];
        __shared__ float sA[4], sB[4];
        float a = w1, b = bcv;
        for (int off = 32; off > 0; off >>= 1) {
            a += __shfl_down(a, off);
            b += __shfl_down(b, off);
        }
        int wave = threadIdx.x >> 6, lane = threadIdx.x & 63;
        if (lane == 0) { sA[wave] = a; sB[wave] = b; }
        __syncthreads();
        if (threadIdx.x == 0) {
            A[o]  = sA[0] + sA[1] + sA[2] + sA[3];
            Bc[o] = sB[0] + sB[1] + sB[2] + sB[3];
        }
    } else {
        int bc = blockIdx.x - 256;  // b*256 + c
        const float* base = x1 + (size_t)bc * 4096;
        int wave = threadIdx.x >> 6;
        int lane = threadIdx.x & 63;
        int doff = lane >> 3, hoff = lane & 7;
        for (int t = wave * 2; t < wave * 2 + 2; ++t) {
            int gd = t >> 2, gh = (t >> 1) & 1, gw = t & 1;
            const float* p = base + (gd * 8 + doff) * 256 + (gh * 8 + hoff) * 16 + gw * 8;
            float4 v0 = *(const float4*)p;
            float4 v1 = *(const float4*)(p + 4);
            float s = v0.x + v0.y + v0.z + v0.w + v1.x + v1.y + v1.z + v1.w;
            for (int off = 32; off > 0; off >>= 1) s += __shfl_down(s, off);
            if (lane == 0) tokens[bc * 8 + t] = s * (1.0f / 512.0f);
        }
    }
}

// ---------------- K2: dwconv + residual + LN + k/v projection -> MFMA fragment layouts ----------------
// kfragG[b][h][kc][lane 64][j 8] bf16: element K[g=lane&15][d=kc*32+(lane>>4)*8+j], rows g>=8 zeroed.
// vfragG[b][h][dtile][l 16][g 8] bf16: element V[g][d=dtile*16+l] (A-frag for PV, lanes 16..63 zero).
__global__ void tokens_all(const float* __restrict__ tokens,
                           const float* __restrict__ dw_w,
                           const float* __restrict__ nkv_w,
                           const float* __restrict__ nkv_b,
                           const float* __restrict__ k_w,
                           const float* __restrict__ v_w,
                           unsigned short* __restrict__ kfragG,
                           unsigned short* __restrict__ vfragG) {
    int b = blockIdx.x >> 6;
    int og = blockIdx.x & 63;
    int c = threadIdx.x;
    __shared__ float t2[256][9];
    __shared__ float u8[8], r8[8];
    float t[8];
    #pragma unroll
    for (int g = 0; g < 8; ++g) t[g] = tokens[(b * 256 + c) * 8 + g];
    float w[27];
    #pragma unroll
    for (int i = 0; i < 27; ++i) w[i] = dw_w[c * 27 + i];
    #pragma unroll
    for (int z = 0; z < 2; ++z)
    #pragma unroll
    for (int y = 0; y < 2; ++y)
    #pragma unroll
    for (int x = 0; x < 2; ++x) {
        float s = 0.f;
        #pragma unroll
        for (int i = 0; i < 3; ++i) {
            int nz = z + i - 1; if (nz < 0 || nz > 1) continue;
            #pragma unroll
            for (int j = 0; j < 3; ++j) {
                int ny = y + j - 1; if (ny < 0 || ny > 1) continue;
                #pragma unroll
                for (int l = 0; l < 3; ++l) {
                    int nx = x + l - 1; if (nx < 0 || nx > 1) continue;
                    s += w[(i * 3 + j) * 3 + l] * t[nz * 4 + ny * 2 + nx];
                }
            }
        }
        int g = z * 4 + y * 2 + x;
        t2[c][g] = t[g] + s;
    }
    __syncthreads();
    if (c < 8) {
        float su = 0.f, sq = 0.f;
        for (int cc = 0; cc < 256; ++cc) { float v = t2[cc][c]; su += v; sq += v * v; }
        float u = su * (1.f / 256.f);
        float var = sq * (1.f / 256.f) - u * u;
        u8[c] = u;
        r8[c] = rsqrtf(var + EPS);
    }
    __syncthreads();
    int wv = threadIdx.x >> 6;
    int lane = threadIdx.x & 63;
    int o = og * 4 + wv;
    float acck[8] = {0,0,0,0,0,0,0,0}, accv[8] = {0,0,0,0,0,0,0,0};
    #pragma unroll
    for (int i = 0; i < 4; ++i) {
        int cc = lane + 64 * i;
        float kw = k_w[o * 256 + cc];
        float vw = v_w[o * 256 + cc];
        float nw = nkv_w[cc], nb2 = nkv_b[cc];
        #pragma unroll
        for (int g = 0; g < 8; ++g) {
            float tv = t2[cc][g];
            acck[g] += kw * (nw * (tv - u8[g]) * r8[g] + nb2);
            accv[g] += vw * tv;
        }
    }
    #pragma unroll
    for (int g = 0; g < 8; ++g)
        for (int off = 32; off > 0; off >>= 1) {
            acck[g] += __shfl_down(acck[g], off);
            accv[g] += __shfl_down(accv[g], off);
        }
    if (lane == 0) {
        int h = o >> 6, dl = o & 63;
        // K fragment scatter (this channel o is the "d" row for head h)
        int kc = dl >> 5, dd = (dl >> 3) & 3, j = dl & 7;
        unsigned short* kb = kfragG + (size_t)(((b * 4 + h) * 2 + kc) * 512) + j;
        #pragma unroll
        for (int g = 0; g < 8; ++g) {
            kb[(g + 16 * dd) * 8] = f2bf(acck[g]);
            kb[(g + 8 + 16 * dd) * 8] = 0;   // zero rows g>=8 of the A-operand
        }
        // V fragment: contiguous 8 bf16
        int dt = dl >> 4, l15 = dl & 15;
        uint4 pk;
        pk.x = (unsigned)f2bf(accv[0]) | ((unsigned)f2bf(accv[1]) << 16);
        pk.y = (unsigned)f2bf(accv[2]) | ((unsigned)f2bf(accv[3]) << 16);
        pk.z = (unsigned)f2bf(accv[4]) | ((unsigned)f2bf(accv[5]) << 16);
        pk.w = (unsigned)f2bf(accv[6]) | ((unsigned)f2bf(accv[7]) << 16);
        *(uint4*)(vfragG + (size_t)(((b * 4 + h) * 4 + dt) * 128) + l15 * 8) = pk;
    }
}

// ---------------- K3: fully fused, 8 waves x 64 positions, MFMA attention ----------------
// LDS 40960 B (XQ 32768 + SCR 8192). __launch_bounds__(512,4): VGPR cap 128.
// ROUND-3 AND ROUND-5 LESSON (twice burned): this kernel's phases need ~70-100 live VGPRs;
// any min-waves/EU > 4 (cap < 128) forces scratch spill -> 3-7x HBM traffic -> 2-3x slower.
// NEVER raise the occupancy bound here. If VGPR alloc lands <=64, HW gives 4 blocks/CU anyway.
// K/V staged NOWHERE: loaded per-wave as MFMA fragments from global (L2-hot, from tokens_all).
// Attention per wave (h=w&3, n-half=w>>2): QK^T = 2 chained mfma(K_frag, q_frag) per 16-n tile;
// softmax = 4 exp/lane + 2 shfl_xor(16); PV = mfma(V^T_frag, P_frag) -- P stays in registers.
// Barriers: B1 staging->GEMM1, B2 ->epilogue, B2b epilogue q->attention (cross-wave), B3 ->GEMM2.
// SCR aliasing: stats part/As/Bs/us/rs (dead by B2b) reused as store-transpose scratch post-B3.
__global__ __launch_bounds__(512, 4)
void fused2(const float* __restrict__ x2,
            const unsigned short* __restrict__ W1b,
            const unsigned short* __restrict__ W2b,
            const float* __restrict__ Ag, const float* __restrict__ Bg,
            const unsigned short* __restrict__ kfragG,
            const unsigned short* __restrict__ vfragG,
            float* __restrict__ out) {
    __shared__ __align__(16) unsigned short XQ[16384];   // 32768 B
    __shared__ __align__(16) float SCR[2048];            // 8192 B
    float* part = SCR;          // [1024] stats partials
    float* As   = SCR + 1024;   // [256]
    float* Bs   = SCR + 1280;   // [256]
    float* us   = SCR + 1536;   // [64]
    float* rs   = SCR + 1600;   // [64]

    const int tid = threadIdx.x;
    const int w = tid >> 6;
    const int lane = tid & 63;
    const int m = lane & 15;
    const int qd = lane >> 4;
    const int n0g = blockIdx.x * 64;
    const int b = n0g >> 15;
    const int pos0 = n0g & 32767;

    if (tid < 256) { As[tid] = Ag[tid]; Bs[tid] = Bg[tid]; }
    const unsigned short* w1p = W1b + (size_t)(32 * w + m) * 32 + qd * 8;
    bhalf8 af1_0 = *(const bhalf8*)(w1p);
    bhalf8 af1_1 = *(const bhalf8*)(w1p + 512);

    // ---- stage: x fp32 -> stats partials + bf16 swizzled tile ----
    {
        const int n4 = tid & 15, cg = tid >> 4;   // cg 0..31
        const float* xb = x2 + (size_t)b * 8388608 + pos0 + n4 * 4;
        float su[4] = {0,0,0,0}, sq[4] = {0,0,0,0};
        #pragma unroll
        for (int cc = 0; cc < 4; ++cc) {
            int p = cg + 32 * cc;   // c-pair 0..127
            int c0 = 2 * p;
            float4 a  = *(const float4*)(xb + (size_t)c0 * 32768);
            float4 bq = *(const float4*)(xb + (size_t)(c0 + 1) * 32768);
            int g = p >> 2, wsub = p & 3;
            float av[4] = {a.x, a.y, a.z, a.w};
            float bv[4] = {bq.x, bq.y, bq.z, bq.w};
            #pragma unroll
            for (int i = 0; i < 4; ++i) {
                su[i] += av[i] + bv[i];
                sq[i] += av[i] * av[i] + bv[i] * bv[i];
                int row = 4 * n4 + i;
                int swz = ((row >> 2) ^ row) & 7;
                unsigned val = (unsigned)f2bf(av[i]) | ((unsigned)f2bf(bv[i]) << 16);
                ((unsigned*)XQ)[row * 128 + ((g ^ swz) << 2) + wsub] = val;
            }
        }
        #pragma unroll
        for (int i = 0; i < 4; ++i) {
            float a2 = su[i], q2 = sq[i];
            a2 += __shfl_down(a2, 16); q2 += __shfl_down(q2, 16);
            a2 += __shfl_down(a2, 32); q2 += __shfl_down(q2, 32);
            if (lane < 16) {
                part[w * 128 + (4 * lane + i) * 2]     = a2;
                part[w * 128 + (4 * lane + i) * 2 + 1] = q2;
            }
        }
    }
    __syncthreads();   // B1

    if (tid < 64) {
        float S = 0.f, Q = 0.f;
        #pragma unroll
        for (int w8 = 0; w8 < 8; ++w8) {
            S += part[w8 * 128 + tid * 2];
            Q += part[w8 * 128 + tid * 2 + 1];
        }
        float mu = S * (1.f / 256.f);
        us[tid] = mu;
        rs[tid] = rsqrtf(Q * (1.f / 256.f) - mu * mu + EPS);
    }

    // ---- GEMM1 ----
    floatx4 acc[2][4];
    #pragma unroll
    for (int i = 0; i < 2; ++i)
        #pragma unroll
        for (int j = 0; j < 4; ++j)
            acc[i][j] = (floatx4){0.f, 0.f, 0.f, 0.f};
    {
        bhalf8 afb[2][2];
        afb[0][0] = af1_0; afb[0][1] = af1_1;
        #pragma unroll
        for (int kc = 0; kc < 8; ++kc) {
            if (kc < 7) {
                afb[(kc + 1) & 1][0] = *(const bhalf8*)(w1p + (kc + 1) * 8192);
                afb[(kc + 1) & 1][1] = *(const bhalf8*)(w1p + (kc + 1) * 8192 + 512);
            }
            bhalf8 bfr[4];
            #pragma unroll
            for (int nt = 0; nt < 4; ++nt) {
                int n = nt * 16 + m;
                int swz = ((n >> 2) ^ n) & 7;
                bfr[nt] = *(const bhalf8*)(XQ + n * 256 + (((4 * kc + qd) ^ swz) << 3));
            }
            #pragma unroll
            for (int t = 0; t < 2; ++t)
                #pragma unroll
                for (int nt = 0; nt < 4; ++nt)
                    acc[t][nt] = __builtin_amdgcn_mfma_f32_16x16x32_bf16(afb[kc & 1][t], bfr[nt], acc[t][nt], 0, 0, 0);
        }
    }
    const unsigned short* w2p = W2b + (size_t)(32 * w + m) * 32 + qd * 8;
    bhalf8 af2_0 = *(const bhalf8*)(w2p);
    bhalf8 af2_1 = *(const bhalf8*)(w2p + 512);
    __syncthreads();   // B2: x-tile free; us/rs visible

    // ---- epilogue 1: LN correction, q -> XQ ----
    #pragma unroll
    for (int t = 0; t < 2; ++t) {
        int ob = 32 * w + 16 * t + 4 * qd;
        floatx4 Af = *(const floatx4*)&As[ob];
        floatx4 Bf = *(const floatx4*)&Bs[ob];
        int gq = ob >> 3, off = ob & 7;
        #pragma unroll
        for (int nt = 0; nt < 4; ++nt) {
            int n = nt * 16 + m;
            int swz = ((n >> 2) ^ n) & 7;
            float uv = us[n], rv = rs[n];
            unsigned p0 = (unsigned)f2bf(rv * (acc[t][nt][0] - uv * Af[0]) + Bf[0])
                        | ((unsigned)f2bf(rv * (acc[t][nt][1] - uv * Af[1]) + Bf[1]) << 16);
            unsigned p1 = (unsigned)f2bf(rv * (acc[t][nt][2] - uv * Af[2]) + Bf[2])
                        | ((unsigned)f2bf(rv * (acc[t][nt][3] - uv * Af[3]) + Bf[3]) << 16);
            uint2 val; val.x = p0; val.y = p1;
            *(uint2*)(XQ + n * 256 + ((gq ^ swz) << 3) + off) = val;
        }
    }
    __syncthreads();   // B2b: q fully written before cross-wave attention reads

    // ---- attention (MFMA): wave w -> head h=w&3, n-half w>>2 ----
    {
        const int h = w & 3;
        const int nh = w >> 2;
        // K fragments: 2 x uint4/lane from global (L2-hot)
        uint4 kf0 = ((const uint4*)(kfragG + (size_t)((b * 4 + h) * 2 + 0) * 512))[lane];
        uint4 kf1 = ((const uint4*)(kfragG + (size_t)((b * 4 + h) * 2 + 1) * 512))[lane];
        // V^T fragments: lanes 0..15 hold data, others zero (B rows g>=8 are zero)
        uint4 vf[4];
        #pragma unroll
        for (int dt = 0; dt < 4; ++dt) {
            uint4 z; z.x = 0; z.y = 0; z.z = 0; z.w = 0;
            if (lane < 16) z = ((const uint4*)(vfragG + (size_t)((b * 4 + h) * 4 + dt) * 128))[lane];
            vf[dt] = z;
        }
        #pragma unroll
        for (int nt2 = 0; nt2 < 2; ++nt2) {
            const int n = (2 * nh + nt2) * 16 + m;
            const int swz = ((n >> 2) ^ n) & 7;
            unsigned short* qrow = XQ + n * 256;
            // QK^T: S[g][n], chained over d
            floatx4 s4 = (floatx4){0.f, 0.f, 0.f, 0.f};
            bhalf8 qf0 = *(const bhalf8*)(qrow + (((h * 8 + qd) ^ swz) << 3));
            bhalf8 qf1 = *(const bhalf8*)(qrow + (((h * 8 + 4 + qd) ^ swz) << 3));
            s4 = __builtin_amdgcn_mfma_f32_16x16x32_bf16(*(const bhalf8*)&kf0, qf0, s4, 0, 0, 0);
            s4 = __builtin_amdgcn_mfma_f32_16x16x32_bf16(*(const bhalf8*)&kf1, qf1, s4, 0, 0, 0);
            // softmax over g: lane holds g = 4*qd + j (valid for qd<2; rows 8..15 discarded)
            float sv0 = s4[0] * 0.125f, sv1 = s4[1] * 0.125f;
            float sv2 = s4[2] * 0.125f, sv3 = s4[3] * 0.125f;
            float m4 = fmaxf(fmaxf(sv0, sv1), fmaxf(sv2, sv3));
            float mm = fmaxf(m4, __shfl_xor(m4, 16));
            float p0 = __expf(sv0 - mm), p1 = __expf(sv1 - mm);
            float p2 = __expf(sv2 - mm), p3 = __expf(sv3 - mm);
            float ss = p0 + p1 + p2 + p3;
            float inv = 1.f / (ss + __shfl_xor(ss, 16));
            p0 *= inv; p1 *= inv; p2 *= inv; p3 *= inv;
            float e0 = __shfl_xor(p0, 16), e1 = __shfl_xor(p1, 16);
            float e2 = __shfl_xor(p2, 16), e3 = __shfl_xor(p3, 16);
            // P B-fragment: lanes qd==0 hold k-rows 0..7 (own g0..3 + partner g4..7), rest zero
            uint4 pbu; pbu.x = 0; pbu.y = 0; pbu.z = 0; pbu.w = 0;
            if (qd == 0) {
                pbu.x = (unsigned)f2bf(p0) | ((unsigned)f2bf(p1) << 16);
                pbu.y = (unsigned)f2bf(p2) | ((unsigned)f2bf(p3) << 16);
                pbu.z = (unsigned)f2bf(e0) | ((unsigned)f2bf(e1) << 16);
                pbu.w = (unsigned)f2bf(e2) | ((unsigned)f2bf(e3) << 16);
            }
            bhalf8 pb = *(const bhalf8*)&pbu;
            // PV: out^T[d][n] per 16-d tile; write bf16 to XQ (swizzled)
            #pragma unroll
            for (int dt = 0; dt < 4; ++dt) {
                floatx4 o4 = (floatx4){0.f, 0.f, 0.f, 0.f};
                o4 = __builtin_amdgcn_mfma_f32_16x16x32_bf16(*(const bhalf8*)&vf[dt], pb, o4, 0, 0, 0);
                int cb = h * 64 + dt * 16 + 4 * qd;   // + rr (0..3)
                int gl = cb >> 3;
                uint2 w2v;
                w2v.x = (unsigned)f2bf(o4[0]) | ((unsigned)f2bf(o4[1]) << 16);
                w2v.y = (unsigned)f2bf(o4[2]) | ((unsigned)f2bf(o4[3]) << 16);
                *(uint2*)(qrow + ((gl ^ swz) << 3) + (cb & 7)) = w2v;
            }
        }
    }
    __syncthreads();   // B3: attn out visible

    // ---- GEMM2 ----
    floatx4 acc2[2][4];
    #pragma unroll
    for (int i = 0; i < 2; ++i)
        #pragma unroll
        for (int j = 0; j < 4; ++j)
            acc2[i][j] = (floatx4){0.f, 0.f, 0.f, 0.f};
    {
        bhalf8 afb[2][2];
        afb[0][0] = af2_0; afb[0][1] = af2_1;
        #pragma unroll
        for (int kc = 0; kc < 8; ++kc) {
            if (kc < 7) {
                afb[(kc + 1) & 1][0] = *(const bhalf8*)(w2p + (kc + 1) * 8192);
                afb[(kc + 1) & 1][1] = *(const bhalf8*)(w2p + (kc + 1) * 8192 + 512);
            }
            bhalf8 bfr[4];
            #pragma unroll
            for (int nt = 0; nt < 4; ++nt) {
                int n = nt * 16 + m;
                int swz = ((n >> 2) ^ n) & 7;
                bfr[nt] = *(const bhalf8*)(XQ + n * 256 + (((4 * kc + qd) ^ swz) << 3));
            }
            #pragma unroll
            for (int t = 0; t < 2; ++t)
                #pragma unroll
                for (int nt = 0; nt < 4; ++nt)
                    acc2[t][nt] = __builtin_amdgcn_mfma_f32_16x16x32_bf16(afb[kc & 1][t], bfr[nt], acc2[t][nt], 0, 0, 0);
        }
    }

    // ---- store: per-wave 16x16 XOR-swizzled LDS transpose (SCR reuse) -> float4 stores ----
    {
        float* tb = SCR + w * 256;
        float* obase = out + (size_t)b * 8388608 + pos0;
        const int ol = lane >> 2, c4 = lane & 3;
        #pragma unroll
        for (int t = 0; t < 2; ++t) {
            #pragma unroll
            for (int nt = 0; nt < 4; ++nt) {
                #pragma unroll
                for (int rr = 0; rr < 4; ++rr) {
                    int row = qd * 4 + rr;
                    tb[row * 16 + (m ^ (row & 12))] = acc2[t][nt][rr];
                }
                float4 vo = *(const float4*)(tb + ol * 16 + ((c4 * 4) ^ (ol & 12)));
                *(float4*)(obase + (size_t)(32 * w + 16 * t + ol) * 32768 + nt * 16 + c4 * 4) = vo;
            }
        }
    }
}

extern "C" void kernel_launch(void* const* d_in, const int* in_sizes, int n_in,
                              void* d_out, int out_size, void* d_ws, size_t ws_size,
                              hipStream_t stream) {
    (void)in_sizes; (void)n_in; (void)out_size; (void)ws_size;
    const float* x2     = (const float*)d_in[0];
    const float* x1_low = (const float*)d_in[1];
    const float* q_w    = (const float*)d_in[2];
    const float* k_w    = (const float*)d_in[3];
    const float* v_w    = (const float*)d_in[4];
    const float* dw_w   = (const float*)d_in[5];
    const float* proj_w = (const float*)d_in[6];
    const float* nq_w   = (const float*)d_in[7];
    const float* nq_b   = (const float*)d_in[8];
    const float* nkv_w  = (const float*)d_in[9];
    const float* nkv_b  = (const float*)d_in[10];
    float* outp = (float*)d_out;

    float* wsf = (float*)d_ws;
    float* Av  = wsf;                                        // 256
    float* Bv  = wsf + 256;                                  // 256
    float* tk  = wsf + 512;                                  // 4096
    unsigned short* kfragG = (unsigned short*)(wsf + 4608);  // 8192 ushorts (2b x 4h x 2kc x 64 x 8)
    unsigned short* vfragG = (unsigned short*)(wsf + 8704);  // 4096 ushorts (2b x 4h x 4dt x 16 x 8)
    unsigned short* W1b = (unsigned short*)(wsf + 10752);    // 65536 ushorts
    unsigned short* W2b = (unsigned short*)(wsf + 43520);    // 65536 ushorts

    pre1<<<768, 256, 0, stream>>>(q_w, proj_w, nq_w, nq_b, W1b, W2b, Av, Bv, x1_low, tk);
    tokens_all<<<128, 256, 0, stream>>>(tk, dw_w, nkv_w, nkv_b, k_w, v_w, kfragG, vfragG);
    fused2<<<1024, 512, 0, stream>>>(x2, W1b, W2b, Av, Bv, kfragG, vfragG, outp);
}